// Round 1
// baseline (405.581 us; speedup 1.0000x reference)
//
#include <hip/hip_runtime.h>
#include <cstddef>

#define H 128
#define W 128
#define TILE_R 32
#define P_THRESH 20

// No-LDS streaming version: each thread privately loads its 6-row x 6-col
// window (rows gi0-1..gi0+4, cols j0-1..j0+4 via lane shuffles) and computes
// 4 rows x 4 cols of output. No __shared__, no __syncthreads, no vmcnt(0)
// barrier drain -- pure dataflow; latency hidden by TLP + ~18 loads in
// flight per thread. Row read amplification 6/4 = 1.5x is absorbed by L1/L2.
__global__ __launch_bounds__(256, 6)
void brown_kernel(const float* __restrict__ inp,
                  const int*  __restrict__ dirp,
                  const int*  __restrict__ prb,
                  float* __restrict__ out)
{
    const int tid   = threadIdx.x;
    const int bid   = blockIdx.x;
    const int slice = bid >> 2;              // 4 row-tiles per slice
    const int r0    = (bid & 3) * TILE_R;
    const size_t base = (size_t)slice * (size_t)(H * W);

    const int cq  = tid & 31;        // col quad (cols j0..j0+3)
    const int rg  = tid >> 5;        // row group 0..7
    const int j0  = cq << 2;
    const int gi0 = r0 + (rg << 2);  // first output row of this thread

    // Load one window row k (global row gi0-1+k): 6 input vals
    // (window cols 0..5 = j0-1..j0+4) and two packed mask words:
    // ma = cols j0-1..j0+2, mb = cols j0+1..j0+4.
    // mask byte: 0..7 = direction if prob<=20, 8 = inactive.
    auto load_row = [&](int k, float v[6], unsigned& ma, unsigned& mb) {
        const int gr  = gi0 - 1 + k;
        const int gri = (gr < 0) ? 1 : ((gr >= H) ? (H - 2) : gr); // reflect row (avg halo)
        const float4 c = ((const float4*)(inp + base + (size_t)gri * W))[cq];
        unsigned mwc;
        if ((unsigned)gr < (unsigned)H) {
            const int4 dv = ((const int4*)(dirp + base + (size_t)gr * W))[cq];
            const int4 pv = ((const int4*)(prb  + base + (size_t)gr * W))[cq];
            const unsigned a  = (pv.x <= P_THRESH) ? (unsigned)dv.x : 8u;
            const unsigned b  = (pv.y <= P_THRESH) ? (unsigned)dv.y : 8u;
            const unsigned cc = (pv.z <= P_THRESH) ? (unsigned)dv.z : 8u;
            const unsigned d  = (pv.w <= P_THRESH) ? (unsigned)dv.w : 8u;
            mwc = a | (b << 8) | (cc << 16) | (d << 24);
        } else {
            mwc = 0x08080808u;       // out-of-image rows never source writes
        }
        // shuffles are outside the divergent region: all 64 lanes participate.
        const float    lf  = __shfl_up(c.w, 1);     // lane cq-1: col j0-1
        const float    rt  = __shfl_down(c.x, 1);   // lane cq+1: col j0+4
        const unsigned mwl = __shfl_up(mwc, 1);
        const unsigned mwr = __shfl_down(mwc, 1);
        v[1] = c.x; v[2] = c.y; v[3] = c.z; v[4] = c.w;
        v[0] = (cq > 0)  ? lf : c.y;   // reflect col -1 -> col 1
        v[5] = (cq < 31) ? rt : c.z;   // reflect col 128 -> col 126
        const unsigned ml = (cq > 0)  ? (mwl >> 24)  : 8u;
        const unsigned mr = (cq < 31) ? (mwr & 255u) : 8u;
        ma = (mwc << 8) | ml;
        mb = (mwc >> 8) | (mr << 24);
    };

    float va[6], vb[6], vc[6];
    unsigned maa, mab, mba, mbb, mca, mcb;
    load_row(0, va, maa, mab);
    load_row(1, vb, mba, mbb);

    #pragma unroll
    for (int rr = 0; rr < 4; ++rr) {
        load_row(rr + 2, vc, mca, mcb);

        const int gi = gi0 + rr;
        float cs[6];
        #pragma unroll
        for (int w = 0; w < 6; ++w) cs[w] = va[w] + vb[w] + vc[w];

        float4 res;
        float* rp = (float*)&res;
        #pragma unroll
        for (int p = 0; p < 4; ++p) {
            const float avg = (cs[p] + cs[p + 1] + cs[p + 2]) * (1.0f / 9.0f);
            // packed window bytes: b0 = m[win p], b1 = m[p+1], b2 = m[p+2]
            const unsigned wTop = (p < 2) ? (maa >> (8 * p)) : (mab >> (8 * (p - 2)));
            const unsigned wMid = (p < 2) ? (mba >> (8 * p)) : (mbb >> (8 * (p - 2)));
            const unsigned wBot = (p < 2) ? (mca >> (8 * p)) : (mcb >> (8 * (p - 2)));

            float val = vb[p + 1];   // input[i][j]
            int dl = -1;             // direction of last A-write
            // A-writes ascending d; source offset = (-di,-dj)
            if (((wBot >> 16) & 255u) == 0u) { val = vc[p + 2]; dl = 0; }
            if (((wBot >>  8) & 255u) == 1u) { val = vc[p + 1]; dl = 1; }
            if (( wBot        & 255u) == 2u) { val = vc[p];     dl = 2; }
            if (((wMid >> 16) & 255u) == 3u) { val = vb[p + 2]; dl = 3; }
            if (( wMid        & 255u) == 5u) { val = vb[p];     dl = 5; }
            if (((wTop >> 16) & 255u) == 6u) { val = va[p + 2]; dl = 6; }
            if (((wTop >>  8) & 255u) == 7u) { val = va[p + 1]; dl = 7; }

            // B-write (avg) at own dir msel; wins iff valid and msel >= dl
            const int msel = (int)((wMid >> 8) & 255u);  // own mask = m[1][p+1]
            const int q3 = (msel * 11) >> 5;             // msel/3 for 0..8
            const int di = q3 - 1;
            const int dj = msel - q3 * 3 - 1;
            const int ti = gi + di;
            const int tj = j0 + p + dj;
            const bool bok = (msel < 8) & ((unsigned)ti < 128u) & ((unsigned)tj < 128u);
            if (bok & (msel >= dl)) val = avg;
            rp[p] = val;
        }
        ((float4*)(out + base + (size_t)gi * W))[cq] = res;

        // rotate sliding window (register renames after full unroll)
        #pragma unroll
        for (int w = 0; w < 6; ++w) { va[w] = vb[w]; vb[w] = vc[w]; }
        maa = mba; mab = mbb; mba = mca; mbb = mcb;
    }
}

extern "C" void kernel_launch(void* const* d_in, const int* in_sizes, int n_in,
                              void* d_out, int out_size, void* d_ws, size_t ws_size,
                              hipStream_t stream) {
    const float* inp  = (const float*)d_in[0];
    const int*   dirp = (const int*)d_in[1];
    const int*   prb  = (const int*)d_in[2];
    float* out = (float*)d_out;

    const int slices = in_sizes[0] / (H * W);   // 2048
    const int grid = slices * (H / TILE_R);     // 8192
    brown_kernel<<<grid, 256, 0, stream>>>(inp, dirp, prb, out);
}

// Round 3
// 395.979 us; speedup vs baseline: 1.0242x; 1.0242x over previous
//
#include <hip/hip_runtime.h>
#include <cstddef>

#define H 128
#define W 128
#define ROWS 8            // output rows per thread
#define WIN (ROWS + 2)    // 10 window rows per thread
#define P_THRESH 20

typedef float nf4 __attribute__((ext_vector_type(4)));   // native vec for nontemporal builtin

// Barrier-free streaming, phase-separated for MLP:
//   phase 1a: issue ALL 10 input-row float4 loads (dest regs held in flight)
//   phase 1b: issue dir/prob int4 loads, pack each row's mask word on arrival
//   phase 1c: halo exchange via shuffles (col j0-1 / j0+4, packed mask bytes)
//   phase 2 : 8 output rows from registers, nontemporal float4 stores
// ROWS=8 -> vertical read amplification 10/8 = 1.25x (was 1.5x at ROWS=4).
// __launch_bounds__(256,4): 128-VGPR budget so the load phase can stay in
// flight (~14 KB/wave); 16 waves/CU x 14 KB covers HBM latency many times.
__global__ __launch_bounds__(256, 4)
void brown_kernel(const float* __restrict__ inp,
                  const int*  __restrict__ dirp,
                  const int*  __restrict__ prb,
                  float* __restrict__ out)
{
    const int tid   = threadIdx.x;
    const int bid   = blockIdx.x;
    const int slice = bid >> 1;              // 2 row-tiles (64 rows) per slice
    const int r0    = (bid & 1) << 6;
    const size_t base = (size_t)slice * (size_t)(H * W);

    const int cq  = tid & 31;        // col quad (cols j0..j0+3)
    const int rg  = tid >> 5;        // row group 0..7
    const int j0  = cq << 2;
    const int gi0 = r0 + rg * ROWS;  // first output row of this thread

    // ---- phase 1a: all input window rows (reflect-clamped for avg halo) ----
    float4 c[WIN];
    #pragma unroll
    for (int k = 0; k < WIN; ++k) {
        const int gr  = gi0 - 1 + k;
        const int gri = (gr < 0) ? 1 : ((gr >= H) ? (H - 2) : gr);
        c[k] = ((const float4*)(inp + base + (size_t)gri * W))[cq];
    }

    // ---- phase 1b: mask words, packed on arrival ----
    // mask byte: 0..7 = direction if prob<=20, 8 = inactive
    unsigned mw[WIN];
    #pragma unroll
    for (int k = 0; k < WIN; ++k) {
        const int gr = gi0 - 1 + k;
        if ((unsigned)gr < (unsigned)H) {
            const int4 dv = ((const int4*)(dirp + base + (size_t)gr * W))[cq];
            const int4 pv = ((const int4*)(prb  + base + (size_t)gr * W))[cq];
            const unsigned a  = (pv.x <= P_THRESH) ? (unsigned)dv.x : 8u;
            const unsigned b  = (pv.y <= P_THRESH) ? (unsigned)dv.y : 8u;
            const unsigned cc = (pv.z <= P_THRESH) ? (unsigned)dv.z : 8u;
            const unsigned d  = (pv.w <= P_THRESH) ? (unsigned)dv.w : 8u;
            mw[k] = a | (b << 8) | (cc << 16) | (d << 24);
        } else {
            mw[k] = 0x08080808u;     // out-of-image rows never source writes
        }
    }

    // ---- phase 1c: halo exchange (uniform control flow; all lanes shuffle) ----
    // window cols 0..5 = j0-1..j0+4; ma = mask cols j0-1..j0+2, mb = j0+1..j0+4
    float lf[WIN], rt[WIN];
    unsigned ma[WIN], mb[WIN];
    #pragma unroll
    for (int k = 0; k < WIN; ++k) {
        const float    l   = __shfl_up(c[k].w, 1);    // lane cq-1: col j0-1
        const float    r   = __shfl_down(c[k].x, 1);  // lane cq+1: col j0+4
        const unsigned mwl = __shfl_up(mw[k], 1);
        const unsigned mwr = __shfl_down(mw[k], 1);
        lf[k] = (cq > 0)  ? l : c[k].y;   // reflect col -1 -> col 1
        rt[k] = (cq < 31) ? r : c[k].z;   // reflect col 128 -> col 126
        const unsigned ml = (cq > 0)  ? (mwl >> 24)  : 8u;
        const unsigned mr = (cq < 31) ? (mwr & 255u) : 8u;
        ma[k] = (mw[k] << 8) | ml;
        mb[k] = (mw[k] >> 8) | (mr << 24);
    }

    // ---- phase 2: compute 8 output rows from registers ----
    #pragma unroll
    for (int rr = 0; rr < ROWS; ++rr) {
        const int gi = gi0 + rr;

        // expand the three window rows (cols 0..5)
        float va[6], vb[6], vc[6];
        va[0] = lf[rr];     va[1] = c[rr].x;   va[2] = c[rr].y;
        va[3] = c[rr].z;    va[4] = c[rr].w;   va[5] = rt[rr];
        vb[0] = lf[rr+1];   vb[1] = c[rr+1].x; vb[2] = c[rr+1].y;
        vb[3] = c[rr+1].z;  vb[4] = c[rr+1].w; vb[5] = rt[rr+1];
        vc[0] = lf[rr+2];   vc[1] = c[rr+2].x; vc[2] = c[rr+2].y;
        vc[3] = c[rr+2].z;  vc[4] = c[rr+2].w; vc[5] = rt[rr+2];

        float cs[6];
        #pragma unroll
        for (int w = 0; w < 6; ++w) cs[w] = va[w] + vb[w] + vc[w];

        const unsigned maa = ma[rr],   mab = mb[rr];
        const unsigned mba = ma[rr+1], mbb = mb[rr+1];
        const unsigned mca = ma[rr+2], mcb = mb[rr+2];

        nf4 res;
        #pragma unroll
        for (int p = 0; p < 4; ++p) {
            const float avg = (cs[p] + cs[p + 1] + cs[p + 2]) * (1.0f / 9.0f);
            // packed window bytes: b0 = m[win p], b1 = m[p+1], b2 = m[p+2]
            const unsigned wTop = (p < 2) ? (maa >> (8 * p)) : (mab >> (8 * (p - 2)));
            const unsigned wMid = (p < 2) ? (mba >> (8 * p)) : (mbb >> (8 * (p - 2)));
            const unsigned wBot = (p < 2) ? (mca >> (8 * p)) : (mcb >> (8 * (p - 2)));

            float val = vb[p + 1];   // input[i][j]
            int dl = -1;             // direction of last A-write
            // A-writes ascending d; source offset = (-di,-dj)
            if (((wBot >> 16) & 255u) == 0u) { val = vc[p + 2]; dl = 0; }
            if (((wBot >>  8) & 255u) == 1u) { val = vc[p + 1]; dl = 1; }
            if (( wBot        & 255u) == 2u) { val = vc[p];     dl = 2; }
            if (((wMid >> 16) & 255u) == 3u) { val = vb[p + 2]; dl = 3; }
            if (( wMid        & 255u) == 5u) { val = vb[p];     dl = 5; }
            if (((wTop >> 16) & 255u) == 6u) { val = va[p + 2]; dl = 6; }
            if (((wTop >>  8) & 255u) == 7u) { val = va[p + 1]; dl = 7; }

            // B-write (avg) at own dir msel; wins iff valid and msel >= dl
            const int msel = (int)((wMid >> 8) & 255u);  // own mask = m[1][p+1]
            const int q3 = (msel * 11) >> 5;             // msel/3 for 0..8
            const int di = q3 - 1;
            const int dj = msel - q3 * 3 - 1;
            const int ti = gi + di;
            const int tj = j0 + p + dj;
            const bool bok = (msel < 8) & ((unsigned)ti < 128u) & ((unsigned)tj < 128u);
            if (bok & (msel >= dl)) val = avg;
            res[p] = val;
        }
        // nontemporal: write-once stream, keep it out of L3 so inputs stay hot
        __builtin_nontemporal_store(res, (nf4*)(out + base + (size_t)gi * W) + cq);
    }
}

extern "C" void kernel_launch(void* const* d_in, const int* in_sizes, int n_in,
                              void* d_out, int out_size, void* d_ws, size_t ws_size,
                              hipStream_t stream) {
    const float* inp  = (const float*)d_in[0];
    const int*   dirp = (const int*)d_in[1];
    const int*   prb  = (const int*)d_in[2];
    float* out = (float*)d_out;

    const int slices = in_sizes[0] / (H * W);   // 2048
    const int grid = slices * 2;                // 64 rows per block -> 4096
    brown_kernel<<<grid, 256, 0, stream>>>(inp, dirp, prb, out);
}

// Round 4
// 392.635 us; speedup vs baseline: 1.0330x; 1.0085x over previous
//
#include <hip/hip_runtime.h>
#include <cstddef>

#define H 128
#define W 128
#define WROWS 8           // output rows per wave
#define LROWS 10          // staged window rows per wave (WROWS + 2)
#define P_THRESH 20

typedef float nf4 __attribute__((ext_vector_type(4)));   // native vec for nontemporal store
typedef __attribute__((address_space(1))) const unsigned int glo_u32;
typedef __attribute__((address_space(3))) unsigned int lds_u32;

// Wave-private staging, NO __syncthreads:
//   each wave owns a 10-row window (8 output rows) in its own LDS region.
//   - mask int4 loads issued FIRST (oldest in vmcnt FIFO -> packing can begin
//     while input DMA still in flight)
//   - input staged via global_load_lds dwordx4 (no dest VGPRs -> deep MLP)
//   - explicit s_waitcnt vmcnt(0) before compute (safety: gload_lds -> ds_read)
//   Waves are fully decoupled: no block-wide barrier drain. Staging read
//   amplification 10/8 = 1.25x, absorbed partially by L3.
__global__ __launch_bounds__(256, 6)
void brown_kernel(const float* __restrict__ inp,
                  const int*  __restrict__ dirp,
                  const int*  __restrict__ prb,
                  float* __restrict__ out)
{
    __shared__ __align__(16) float s_in[4 * LROWS * W];   // 20480 B
    __shared__ unsigned int        s_mk[4 * LROWS * 32];  //  5120 B

    const int tid   = threadIdx.x;
    const int wid   = tid >> 6;          // wave 0..3
    const int lane  = tid & 63;
    const int bid   = blockIdx.x;
    const int slice = bid >> 2;          // 4 blocks (32 rows) per slice
    const int r0    = (bid & 3) << 5;
    const int wr0   = r0 + wid * WROWS;  // first output row of this wave
    const size_t base = (size_t)slice * (size_t)(H * W);

    float*        s_in_w = s_in + wid * (LROWS * W);
    unsigned int* s_mk_w = s_mk + wid * (LROWS * 32);

    // ---- stage (wave-private): 10 rows x 32 words = 320 = 5 exact wave-iters ----
    // 1) mask int4 loads (issued first: oldest in vmcnt FIFO)
    int4 dvv[5], pvv[5];
    #pragma unroll
    for (int w = 0; w < 5; ++w) {
        const int idx = w * 64 + lane;
        const int L   = idx >> 5;
        const int c4  = idx & 31;
        const int gr  = wr0 - 1 + L;
        if ((unsigned)gr < (unsigned)H) {
            dvv[w] = ((const int4*)(dirp + base + (size_t)gr * W))[c4];
            pvv[w] = ((const int4*)(prb  + base + (size_t)gr * W))[c4];
        } else {
            dvv[w] = make_int4(8, 8, 8, 8);
            pvv[w] = make_int4(100, 100, 100, 100);  // > P_THRESH -> inactive
        }
    }
    // 2) input rows via async DMA to wave-private LDS (reflect-clamped rows)
    #pragma unroll
    for (int w = 0; w < 5; ++w) {
        const int idx = w * 64 + lane;
        const int L   = idx >> 5;
        const int c4  = idx & 31;
        const int gr  = wr0 - 1 + L;
        const int gri = (gr < 0) ? 1 : ((gr >= H) ? (H - 2) : gr);
        const float* gp = inp + base + (size_t)gri * W + c4 * 4;
        __builtin_amdgcn_global_load_lds((glo_u32*)gp, (lds_u32*)(s_in_w + idx * 4), 16, 0, 0);
    }
    // 3) pack masks -> LDS bytes (data-dep waits only the mask loads' vmcnt slots)
    //    mask byte: 0..7 = direction if prob<=20, 8 = inactive
    #pragma unroll
    for (int w = 0; w < 5; ++w) {
        const int idx = w * 64 + lane;
        const unsigned a  = (pvv[w].x <= P_THRESH) ? (unsigned)dvv[w].x : 8u;
        const unsigned b  = (pvv[w].y <= P_THRESH) ? (unsigned)dvv[w].y : 8u;
        const unsigned cc = (pvv[w].z <= P_THRESH) ? (unsigned)dvv[w].z : 8u;
        const unsigned d  = (pvv[w].w <= P_THRESH) ? (unsigned)dvv[w].w : 8u;
        s_mk_w[idx] = a | (b << 8) | (cc << 16) | (d << 24);
    }
    // ensure gload_lds DMA landed before any ds_read of s_in (wave-private: no barrier)
    asm volatile("s_waitcnt vmcnt(0)" ::: "memory");

    // ---- compute: 2 row-halves x 4 rows/lane, 4 cols/lane (sliding window) ----
    const int cq   = lane & 31;          // col quad (cols j0..j0+3)
    const int rh   = lane >> 6 ? 0 : (lane >> 5);  // 0 or 1 (row half)
    const int j0   = cq << 2;
    const int lrb  = rh << 2;            // local window row of top for rr=0
    const int cqm1 = (cq > 0)  ? cq - 1 : 0;
    const int cqp1 = (cq < 31) ? cq + 1 : 31;

    // load one window row L: 6 input vals (cols j0-1..j0+4) + packed masks
    // ma = cols j0-1..j0+2, mb = cols j0+1..j0+4
    auto load_row = [&](int L, float v[6], unsigned& ma, unsigned& mb) {
        const float4   c   = ((const float4*)(s_in_w + L * W))[cq];
        const unsigned mwc = s_mk_w[L * 32 + cq];
        const unsigned mwl = s_mk_w[L * 32 + cqm1];
        const unsigned mwr = s_mk_w[L * 32 + cqp1];
        const float lf = __shfl_up(c.w, 1);    // lane cq-1: col j0-1 (guarded)
        const float rt = __shfl_down(c.x, 1);  // lane cq+1: col j0+4 (guarded)
        v[1] = c.x; v[2] = c.y; v[3] = c.z; v[4] = c.w;
        v[0] = (cq > 0)  ? lf : c.y;   // reflect col -1 -> col 1
        v[5] = (cq < 31) ? rt : c.z;   // reflect col 128 -> col 126
        const unsigned ml = (cq > 0)  ? (mwl >> 24)  : 8u;
        const unsigned mr = (cq < 31) ? (mwr & 255u) : 8u;
        ma = (mwc << 8) | ml;
        mb = (mwc >> 8) | (mr << 24);
    };

    float va[6], vb[6], vc[6];
    unsigned maa, mab, mba, mbb, mca, mcb;
    load_row(lrb + 0, va, maa, mab);
    load_row(lrb + 1, vb, mba, mbb);

    #pragma unroll
    for (int rr = 0; rr < 4; ++rr) {
        load_row(lrb + rr + 2, vc, mca, mcb);

        const int gi = wr0 + (rh << 2) + rr;
        float cs[6];
        #pragma unroll
        for (int w = 0; w < 6; ++w) cs[w] = va[w] + vb[w] + vc[w];

        nf4 res;
        #pragma unroll
        for (int p = 0; p < 4; ++p) {
            const float avg = (cs[p] + cs[p + 1] + cs[p + 2]) * (1.0f / 9.0f);
            // packed window bytes: b0 = m[win p], b1 = m[p+1], b2 = m[p+2]
            const unsigned wTop = (p < 2) ? (maa >> (8 * p)) : (mab >> (8 * (p - 2)));
            const unsigned wMid = (p < 2) ? (mba >> (8 * p)) : (mbb >> (8 * (p - 2)));
            const unsigned wBot = (p < 2) ? (mca >> (8 * p)) : (mcb >> (8 * (p - 2)));

            float val = vb[p + 1];   // input[i][j]
            int dl = -1;             // direction of last A-write
            // A-writes ascending d; source offset = (-di,-dj)
            if (((wBot >> 16) & 255u) == 0u) { val = vc[p + 2]; dl = 0; }
            if (((wBot >>  8) & 255u) == 1u) { val = vc[p + 1]; dl = 1; }
            if (( wBot        & 255u) == 2u) { val = vc[p];     dl = 2; }
            if (((wMid >> 16) & 255u) == 3u) { val = vb[p + 2]; dl = 3; }
            if (( wMid        & 255u) == 5u) { val = vb[p];     dl = 5; }
            if (((wTop >> 16) & 255u) == 6u) { val = va[p + 2]; dl = 6; }
            if (((wTop >>  8) & 255u) == 7u) { val = va[p + 1]; dl = 7; }

            // B-write (avg) at own dir msel; wins iff valid and msel >= dl
            const int msel = (int)((wMid >> 8) & 255u);  // own mask = m[1][p+1]
            const int q3 = (msel * 11) >> 5;             // msel/3 for 0..8
            const int di = q3 - 1;
            const int dj = msel - q3 * 3 - 1;
            const int ti = gi + di;
            const int tj = j0 + p + dj;
            const bool bok = (msel < 8) & ((unsigned)ti < 128u) & ((unsigned)tj < 128u);
            if (bok & (msel >= dl)) val = avg;
            res[p] = val;
        }
        __builtin_nontemporal_store(res, (nf4*)(out + base + (size_t)gi * W) + cq);

        // rotate sliding window
        #pragma unroll
        for (int w = 0; w < 6; ++w) { va[w] = vb[w]; vb[w] = vc[w]; }
        maa = mba; mab = mbb; mba = mca; mbb = mcb;
    }
}

extern "C" void kernel_launch(void* const* d_in, const int* in_sizes, int n_in,
                              void* d_out, int out_size, void* d_ws, size_t ws_size,
                              hipStream_t stream) {
    const float* inp  = (const float*)d_in[0];
    const int*   dirp = (const int*)d_in[1];
    const int*   prb  = (const int*)d_in[2];
    float* out = (float*)d_out;

    const int slices = in_sizes[0] / (H * W);   // 2048
    const int grid = slices * 4;                // 32 rows per block -> 8192
    brown_kernel<<<grid, 256, 0, stream>>>(inp, dirp, prb, out);
}